// Round 1
// baseline (1533.408 us; speedup 1.0000x reference)
//
#include <hip/hip_runtime.h>

typedef unsigned short u16;
typedef u16 u16x8 __attribute__((ext_vector_type(8)));
typedef __bf16 bf16x8 __attribute__((ext_vector_type(8)));
typedef float f32x4 __attribute__((ext_vector_type(4)));

#define TOKENS 4096
#define DMODEL 4096
#define NHEAD 32
#define NKV 8
#define DHEAD 128
#define SEQ 2048

__device__ inline u16 f2bf(float f) {
    unsigned int u = __float_as_uint(f);
    u += 0x7fffu + ((u >> 16) & 1u);
    return (u16)(u >> 16);
}
__device__ inline float bf2f(u16 h) {
    return __uint_as_float(((unsigned int)h) << 16);
}
__device__ inline f32x4 mfma16(bf16x8 a, bf16x8 b, f32x4 c) {
    return __builtin_amdgcn_mfma_f32_16x16x32_bf16(a, b, c, 0, 0, 0);
}

// ---------------- fp32 -> bf16 convert (x) ----------------
__global__ __launch_bounds__(256) void f2bf_kernel(const float* __restrict__ in,
                                                   u16* __restrict__ out, int n) {
    int i = (blockIdx.x * 256 + threadIdx.x) * 4;
    if (i >= n) return;
    float4 v = *(const float4*)(in + i);
    u16 o0 = f2bf(v.x), o1 = f2bf(v.y), o2 = f2bf(v.z), o3 = f2bf(v.w);
    u16* p = out + i;
    p[0] = o0; p[1] = o1; p[2] = o2; p[3] = o3;
}

// ---------------- transpose + convert: w[K][N] fp32 -> wt[N][K] bf16 ----------------
__global__ __launch_bounds__(256) void transpose_kernel(const float* __restrict__ in,
                                                        u16* __restrict__ out,
                                                        int K, int N) {
    __shared__ float t[32][33];
    int n0 = blockIdx.x * 32, k0 = blockIdx.y * 32;
    int x = threadIdx.x, y = threadIdx.y;
#pragma unroll
    for (int i = 0; i < 4; i++)
        t[y + 8 * i][x] = in[(size_t)(k0 + y + 8 * i) * N + n0 + x];
    __syncthreads();
#pragma unroll
    for (int i = 0; i < 4; i++)
        out[(size_t)(n0 + y + 8 * i) * K + k0 + x] = f2bf(t[x][y + 8 * i]);
}

// ---------------- GEMM: C[M][N] = A[M][K] * Bt[N][K]^T  (bf16 in, fp32 acc) -------
// 128x128 tile, BK=32, 4 waves (each 64x64 = 4x4 mfma 16x16x32 tiles)
#define LDT 40  // padded LDS row stride in elements (80B: 16B aligned, 2-way banks)

template <bool OUT_F32>
__global__ __launch_bounds__(256, 2) void gemm_bt(const u16* __restrict__ A,
                                                  const u16* __restrict__ Bt,
                                                  void* __restrict__ C,
                                                  int M, int N, int K) {
    __shared__ u16 lA[128 * LDT];
    __shared__ u16 lB[128 * LDT];
    int tid = threadIdx.x;
    int wave = tid >> 6, lane = tid & 63;
    int quad = lane >> 4, l16 = lane & 15;
    int m0 = blockIdx.y * 128, n0 = blockIdx.x * 128;
    int wm = (wave >> 1) * 64, wn = (wave & 1) * 64;
    int sr = tid >> 2;          // 0..63
    int sc = (tid & 3) * 8;     // 0,8,16,24

    f32x4 acc[4][4];
#pragma unroll
    for (int i = 0; i < 4; i++)
#pragma unroll
        for (int j = 0; j < 4; j++) acc[i][j] = (f32x4){0.f, 0.f, 0.f, 0.f};

    for (int k0 = 0; k0 < K; k0 += 32) {
        u16x8 a0 = *(const u16x8*)(A + (size_t)(m0 + sr) * K + k0 + sc);
        u16x8 a1 = *(const u16x8*)(A + (size_t)(m0 + sr + 64) * K + k0 + sc);
        u16x8 b0 = *(const u16x8*)(Bt + (size_t)(n0 + sr) * K + k0 + sc);
        u16x8 b1 = *(const u16x8*)(Bt + (size_t)(n0 + sr + 64) * K + k0 + sc);
        if (k0) __syncthreads();
        *(u16x8*)(lA + sr * LDT + sc) = a0;
        *(u16x8*)(lA + (sr + 64) * LDT + sc) = a1;
        *(u16x8*)(lB + sr * LDT + sc) = b0;
        *(u16x8*)(lB + (sr + 64) * LDT + sc) = b1;
        __syncthreads();

        bf16x8 af[4], bf[4];
#pragma unroll
        for (int i = 0; i < 4; i++)
            af[i] = *(const bf16x8*)(lA + (wm + i * 16 + l16) * LDT + quad * 8);
#pragma unroll
        for (int j = 0; j < 4; j++)
            bf[j] = *(const bf16x8*)(lB + (wn + j * 16 + l16) * LDT + quad * 8);
#pragma unroll
        for (int i = 0; i < 4; i++)
#pragma unroll
            for (int j = 0; j < 4; j++)
                acc[i][j] = mfma16(af[i], bf[j], acc[i][j]);
    }

#pragma unroll
    for (int i = 0; i < 4; i++)
#pragma unroll
        for (int j = 0; j < 4; j++) {
            int row = m0 + wm + i * 16 + quad * 4;
            int col = n0 + wn + j * 16 + l16;
            if (OUT_F32) {
                float* Cf = (float*)C;
#pragma unroll
                for (int r = 0; r < 4; r++)
                    Cf[(size_t)(row + r) * N + col] = acc[i][j][r];
            } else {
                u16* Cb = (u16*)C;
#pragma unroll
                for (int r = 0; r < 4; r++)
                    Cb[(size_t)(row + r) * N + col] = f2bf(acc[i][j][r]);
            }
        }
}

// ---------------- RoPE (in-place on bf16 buffer [tok][h*128+d]) ----------------
__global__ __launch_bounds__(256) void rope_kernel(u16* __restrict__ buf,
                                                   const float* __restrict__ cosb,
                                                   const float* __restrict__ sinb,
                                                   int nheads) {
    int idx = blockIdx.x * 256 + threadIdx.x;
    int total = TOKENS * nheads * 64;
    if (idx >= total) return;
    int p = idx & 63;
    int rest = idx >> 6;
    int h = rest % nheads;
    int tok = rest / nheads;
    int tseq = tok & (SEQ - 1);
    float c = cosb[tseq * 64 + p], s = sinb[tseq * 64 + p];
    u16* ptr = buf + ((size_t)tok * nheads + h) * DHEAD + 2 * p;
    float xr = bf2f(ptr[0]), xi = bf2f(ptr[1]);
    ptr[0] = f2bf(xr * c - xi * s);
    ptr[1] = f2bf(xr * s + xi * c);
}

// ---------------- Flash attention ----------------
// grid: (qtile 0..31, head 0..31, b 0..1); 256 threads = 4 waves; 64 q rows/block,
// 16 q rows/wave; 32-key tiles. Q/K layouts natural [tok][h*128+d]; V staged
// transposed in LDS for the PV B-operand.
#define LDK 160  // K tile LDS row stride (elems)
#define LDV 40   // V^T / P LDS row stride

__global__ __launch_bounds__(256, 2) void flash_kernel(const u16* __restrict__ Q,
                                                       const u16* __restrict__ Kb,
                                                       const u16* __restrict__ Vb,
                                                       u16* __restrict__ Z) {
    __shared__ u16 lK[32 * LDK];
    __shared__ u16 lV[128 * LDV];
    __shared__ u16 lP[4][16 * LDV];
    int tid = threadIdx.x;
    int wave = tid >> 6, lane = tid & 63;
    int quad = lane >> 4, l16 = lane & 15;
    int qt = blockIdx.x, h = blockIdx.y, b = blockIdx.z;
    int kvh = h >> 2;
    int q0w = qt * 64 + wave * 16;
    const float scale = 0.08838834764831845f;  // 1/sqrt(128)

    // Q fragments: 16 rows x 128 d -> 4 A-frags
    bf16x8 qf[4];
    const u16* qptr = Q + ((size_t)(b * SEQ + q0w + l16)) * DMODEL + h * DHEAD;
#pragma unroll
    for (int kk = 0; kk < 4; kk++)
        qf[kk] = *(const bf16x8*)(qptr + kk * 32 + quad * 8);

    f32x4 o[8];
#pragma unroll
    for (int nt = 0; nt < 8; nt++) o[nt] = (f32x4){0.f, 0.f, 0.f, 0.f};
    float mrow[4] = {-__builtin_inff(), -__builtin_inff(), -__builtin_inff(), -__builtin_inff()};
    float lrow[4] = {0.f, 0.f, 0.f, 0.f};

    int nkt = 2 * qt + 2;
    int sk = tid >> 4, sd = (tid & 15) * 8;  // staging: key row, d offset

    for (int kt = 0; kt < nkt; kt++) {
        int key0 = kt * 32;
        const u16* kp = Kb + ((size_t)(b * SEQ + key0 + sk)) * (NKV * DHEAD) + kvh * DHEAD + sd;
        const u16* vp = Vb + ((size_t)(b * SEQ + key0 + sk)) * (NKV * DHEAD) + kvh * DHEAD + sd;
        u16x8 k0v = *(const u16x8*)kp;
        u16x8 k1v = *(const u16x8*)(kp + 16 * (NKV * DHEAD));
        u16x8 v0 = *(const u16x8*)vp;
        u16x8 v1 = *(const u16x8*)(vp + 16 * (NKV * DHEAD));
        if (kt) __syncthreads();
        *(u16x8*)(lK + sk * LDK + sd) = k0v;
        *(u16x8*)(lK + (sk + 16) * LDK + sd) = k1v;
#pragma unroll
        for (int j = 0; j < 8; j++) {
            lV[(sd + j) * LDV + sk] = v0[j];
            lV[(sd + j) * LDV + sk + 16] = v1[j];
        }
        __syncthreads();

        if (key0 <= q0w + 15) {
            // S = Q K^T for 16 q rows x 32 keys
            f32x4 s[2];
#pragma unroll
            for (int sub = 0; sub < 2; sub++) {
                f32x4 a = (f32x4){0.f, 0.f, 0.f, 0.f};
#pragma unroll
                for (int kk = 0; kk < 4; kk++) {
                    bf16x8 kf = *(const bf16x8*)(lK + (sub * 16 + l16) * LDK + kk * 32 + quad * 8);
                    a = mfma16(qf[kk], kf, a);
                }
                s[sub] = a;
            }
            float tmax[4];
#pragma unroll
            for (int r = 0; r < 4; r++) {
                int q = q0w + quad * 4 + r;
                s[0][r] *= scale;
                s[1][r] *= scale;
                if (key0 + l16 > q) s[0][r] = -__builtin_inff();
                if (key0 + 16 + l16 > q) s[1][r] = -__builtin_inff();
                tmax[r] = fmaxf(s[0][r], s[1][r]);
            }
#pragma unroll
            for (int off = 1; off < 16; off <<= 1)
#pragma unroll
                for (int r = 0; r < 4; r++)
                    tmax[r] = fmaxf(tmax[r], __shfl_xor(tmax[r], off, 16));
            float al[4], tsum[4];
#pragma unroll
            for (int r = 0; r < 4; r++) {
                float mnew = fmaxf(mrow[r], tmax[r]);
                al[r] = __expf(mrow[r] - mnew);
                mrow[r] = mnew;
                s[0][r] = __expf(s[0][r] - mnew);
                s[1][r] = __expf(s[1][r] - mnew);
                tsum[r] = s[0][r] + s[1][r];
            }
#pragma unroll
            for (int off = 1; off < 16; off <<= 1)
#pragma unroll
                for (int r = 0; r < 4; r++) tsum[r] += __shfl_xor(tsum[r], off, 16);
#pragma unroll
            for (int r = 0; r < 4; r++) lrow[r] = lrow[r] * al[r] + tsum[r];
            // P -> LDS (C-layout -> A-layout round trip)
#pragma unroll
            for (int r = 0; r < 4; r++) {
                lP[wave][(quad * 4 + r) * LDV + l16] = f2bf(s[0][r]);
                lP[wave][(quad * 4 + r) * LDV + 16 + l16] = f2bf(s[1][r]);
            }
            bf16x8 pf = *(const bf16x8*)(&lP[wave][l16 * LDV + quad * 8]);
#pragma unroll
            for (int nt = 0; nt < 8; nt++) {
                f32x4 ov = o[nt];
#pragma unroll
                for (int r = 0; r < 4; r++) ov[r] *= al[r];
                bf16x8 vf = *(const bf16x8*)(lV + (nt * 16 + l16) * LDV + quad * 8);
                o[nt] = mfma16(pf, vf, ov);
            }
        }
    }
    // epilogue: O /= l, write z (bf16) at [tok][h*128+d]
#pragma unroll
    for (int nt = 0; nt < 8; nt++)
#pragma unroll
        for (int r = 0; r < 4; r++) {
            int q = q0w + quad * 4 + r;
            float val = o[nt][r] / lrow[r];
            Z[((size_t)(b * SEQ + q)) * DMODEL + h * DHEAD + nt * 16 + l16] = f2bf(val);
        }
}

extern "C" void kernel_launch(void* const* d_in, const int* in_sizes, int n_in,
                              void* d_out, int out_size, void* d_ws, size_t ws_size,
                              hipStream_t stream) {
    const float* x    = (const float*)d_in[0];
    const float* fcos = (const float*)d_in[1];
    const float* fsin = (const float*)d_in[2];
    const float* wq   = (const float*)d_in[3];
    const float* wk   = (const float*)d_in[4];
    const float* wv   = (const float*)d_in[5];
    const float* wo   = (const float*)d_in[6];
    float* out = (float*)d_out;
    char* ws = (char*)d_ws;

    u16* xb  = (u16*)(ws);                  // 32MB  [4096][4096]
    u16* qb  = (u16*)(ws + 33554432ull);    // 32MB  [4096][4096]
    u16* kb  = (u16*)(ws + 67108864ull);    // 8MB   [4096][1024]
    u16* vb  = (u16*)(ws + 75497472ull);    // 8MB   [4096][1024]
    u16* zb  = (u16*)(ws + 83886080ull);    // 32MB  [4096][4096]
    u16* wqt = (u16*)(ws + 117440512ull);   // 32MB  [4096][4096] (transposed)
    u16* wkt = (u16*)(ws + 150994944ull);   // 8MB   [1024][4096]
    u16* wvt = (u16*)(ws + 159383552ull);   // 8MB   [1024][4096]
    u16* wot = (u16*)(ws + 167772160ull);   // 32MB  [4096][4096]

    f2bf_kernel<<<16384, 256, 0, stream>>>(x, xb, TOKENS * DMODEL);
    dim3 tb(32, 8);
    transpose_kernel<<<dim3(128, 128), tb, 0, stream>>>(wq, wqt, 4096, 4096);
    transpose_kernel<<<dim3(32, 128), tb, 0, stream>>>(wk, wkt, 4096, 1024);
    transpose_kernel<<<dim3(32, 128), tb, 0, stream>>>(wv, wvt, 4096, 1024);
    transpose_kernel<<<dim3(128, 128), tb, 0, stream>>>(wo, wot, 4096, 4096);

    gemm_bt<false><<<dim3(32, 32), 256, 0, stream>>>(xb, wqt, qb, 4096, 4096, 4096);
    gemm_bt<false><<<dim3(8, 32), 256, 0, stream>>>(xb, wkt, kb, 4096, 1024, 4096);
    gemm_bt<false><<<dim3(8, 32), 256, 0, stream>>>(xb, wvt, vb, 4096, 1024, 4096);

    rope_kernel<<<32768, 256, 0, stream>>>(qb, fcos, fsin, NHEAD);
    rope_kernel<<<8192, 256, 0, stream>>>(kb, fcos, fsin, NKV);

    flash_kernel<<<dim3(32, 32, 2), 256, 0, stream>>>(qb, kb, vb, zb);

    gemm_bt<true><<<dim3(32, 32), 256, 0, stream>>>(zb, wot, out, 4096, 4096, 4096);
}

// Round 2
// 843.432 us; speedup vs baseline: 1.8181x; 1.8181x over previous
//
#include <hip/hip_runtime.h>

typedef unsigned short u16;
typedef unsigned int u32;
typedef u16 u16x8 __attribute__((ext_vector_type(8)));
typedef __bf16 bf16x8 __attribute__((ext_vector_type(8)));
typedef float f32x4 __attribute__((ext_vector_type(4)));

#define TOKENS 4096
#define DMODEL 4096
#define QKVN 6144
#define NHEAD 32
#define NKV 8
#define DHEAD 128
#define SEQ 2048

__device__ inline u16 f2bf(float f) {
    unsigned int u = __float_as_uint(f);
    u += 0x7fffu + ((u >> 16) & 1u);
    return (u16)(u >> 16);
}
__device__ inline float bf2f(u16 h) {
    return __uint_as_float(((unsigned int)h) << 16);
}
__device__ inline u32 pack2bf(float a, float b) {
    return (u32)f2bf(a) | ((u32)f2bf(b) << 16);
}
__device__ inline f32x4 mfma16(bf16x8 a, bf16x8 b, f32x4 c) {
    return __builtin_amdgcn_mfma_f32_16x16x32_bf16(a, b, c, 0, 0, 0);
}
__device__ __forceinline__ void gload16(const u16* g, u16* l) {
    __builtin_amdgcn_global_load_lds((const __attribute__((address_space(1))) u32*)g,
                                     (__attribute__((address_space(3))) u32*)l, 16, 0, 0);
}

// ---------------- fp32 -> bf16 convert ----------------
__global__ __launch_bounds__(256) void f2bf_kernel(const float* __restrict__ in,
                                                   u16* __restrict__ out, int n) {
    int i = (blockIdx.x * 256 + threadIdx.x) * 4;
    if (i >= n) return;
    float4 v = *(const float4*)(in + i);
    u16 o0 = f2bf(v.x), o1 = f2bf(v.y), o2 = f2bf(v.z), o3 = f2bf(v.w);
    u16* p = out + i;
    p[0] = o0; p[1] = o1; p[2] = o2; p[3] = o3;
}

// ---------------- transpose + convert: w[K][N] fp32 -> wt[N][K] bf16 ----------------
__global__ __launch_bounds__(256) void transpose_kernel(const float* __restrict__ in,
                                                        u16* __restrict__ out,
                                                        int K, int N) {
    __shared__ float t[32][33];
    int n0 = blockIdx.x * 32, k0 = blockIdx.y * 32;
    int x = threadIdx.x, y = threadIdx.y;
#pragma unroll
    for (int i = 0; i < 4; i++)
        t[y + 8 * i][x] = in[(size_t)(k0 + y + 8 * i) * N + n0 + x];
    __syncthreads();
#pragma unroll
    for (int i = 0; i < 4; i++)
        out[(size_t)(n0 + y + 8 * i) * K + k0 + x] = f2bf(t[x][y + 8 * i]);
}

// ---------------- bf16 transpose for V: qkv cols [5120..6144) -> vt[b][dcol][seq] ----
__global__ __launch_bounds__(256) void vtrans_kernel(const u16* __restrict__ qkv,
                                                     u16* __restrict__ vt) {
    __shared__ u16 t[32][33];
    int b = blockIdx.z;
    int c0 = blockIdx.x * 32;  // dcol (kvh*128+d), 0..1023
    int r0 = blockIdx.y * 32;  // tok within seq, 0..2047
    int x = threadIdx.x, y = threadIdx.y;
    const u16* in = qkv + (size_t)(b * SEQ) * QKVN + 5120;
#pragma unroll
    for (int i = 0; i < 4; i++)
        t[y + 8 * i][x] = in[(size_t)(r0 + y + 8 * i) * QKVN + c0 + x];
    __syncthreads();
    u16* out = vt + (size_t)b * 1024 * SEQ;
#pragma unroll
    for (int i = 0; i < 4; i++)
        out[(size_t)(c0 + y + 8 * i) * SEQ + r0 + x] = t[x][y + 8 * i];
}

// ---------------- GEMM (m97 structure): C[M][N] = A[M][K] * Bt[N][K]^T ----------------
// 128x128 tile, BK=32, global_load_lds width16, unpadded 32-elem LDS rows.
template <bool OUT_F32>
__global__ __launch_bounds__(256, 2) void gemm_lds(const u16* __restrict__ A,
                                                   const u16* __restrict__ Bt,
                                                   void* __restrict__ C,
                                                   int M, int N, int K) {
    __shared__ u16 lA[128 * 32];
    __shared__ u16 lB[128 * 32];
    int tid = threadIdx.x, wave = tid >> 6, lane = tid & 63;
    int quad = lane >> 4, l16 = lane & 15;
    int m0 = blockIdx.y * 128, n0 = blockIdx.x * 128;
    int wm = (wave >> 1) * 64, wn = (wave & 1) * 64;
    int lrow = lane >> 2, lcol = (lane & 3) * 8;

    const u16* ga = A + (size_t)(m0 + wave * 32 + lrow) * K + lcol;
    const u16* gb = Bt + (size_t)(n0 + wave * 32 + lrow) * K + lcol;
    u16* la = lA + (wave * 32) * 32;
    u16* lb = lB + (wave * 32) * 32;

    f32x4 acc[4][4] = {};

    gload16(ga, la);
    gload16(ga + (size_t)16 * K, la + 512);
    gload16(gb, lb);
    gload16(gb + (size_t)16 * K, lb + 512);

    for (int k0 = 0; k0 < K; k0 += 32) {
        __syncthreads();  // drains vmcnt: staged tile ready
        bf16x8 af[4], bfr[4];
#pragma unroll
        for (int i = 0; i < 4; i++)
            af[i] = *(const bf16x8*)(lA + (wm + i * 16 + l16) * 32 + quad * 8);
#pragma unroll
        for (int j = 0; j < 4; j++)
            bfr[j] = *(const bf16x8*)(lB + (wn + j * 16 + l16) * 32 + quad * 8);
        if (k0 + 32 < K) {
            __syncthreads();  // all waves' frag reads done; safe to overwrite
            gload16(ga + k0 + 32, la);
            gload16(ga + (size_t)16 * K + k0 + 32, la + 512);
            gload16(gb + k0 + 32, lb);
            gload16(gb + (size_t)16 * K + k0 + 32, lb + 512);
        }
#pragma unroll
        for (int i = 0; i < 4; i++)
#pragma unroll
            for (int j = 0; j < 4; j++)
                acc[i][j] = mfma16(af[i], bfr[j], acc[i][j]);
    }

#pragma unroll
    for (int i = 0; i < 4; i++)
#pragma unroll
        for (int j = 0; j < 4; j++) {
            int row = m0 + wm + i * 16 + quad * 4;
            int col = n0 + wn + j * 16 + l16;
            if (OUT_F32) {
                float* Cf = (float*)C;
#pragma unroll
                for (int r = 0; r < 4; r++)
                    Cf[(size_t)(row + r) * N + col] = acc[i][j][r];
            } else {
                u16* Cb = (u16*)C;
#pragma unroll
                for (int r = 0; r < 4; r++)
                    Cb[(size_t)(row + r) * N + col] = f2bf(acc[i][j][r]);
            }
        }
}

// ---------------- RoPE on fused qkv buffer (packed u32, optional scale fold) --------
__global__ __launch_bounds__(256) void rope2_kernel(u16* __restrict__ buf,
                                                    const float* __restrict__ cosb,
                                                    const float* __restrict__ sinb,
                                                    int nheads, int colbase, float scale) {
    int idx = blockIdx.x * 256 + threadIdx.x;
    int p = idx & 63;
    int rest = idx >> 6;
    int h = rest & (nheads - 1);
    int tok = rest / nheads;
    int tseq = tok & (SEQ - 1);
    float c = cosb[tseq * 64 + p], s = sinb[tseq * 64 + p];
    u32* ptr = (u32*)(buf + (size_t)tok * QKVN + colbase + h * DHEAD + 2 * p);
    u32 v = *ptr;
    float xr = bf2f((u16)(v & 0xffff)), xi = bf2f((u16)(v >> 16));
    float orr = (xr * c - xi * s) * scale;
    float oii = (xr * s + xi * c) * scale;
    *ptr = pack2bf(orr, oii);
}

// ---------------- Flash attention v2 ----------------
// grid (16, 32, 2) = (qtile, head, b), 256 thr = 4 waves. Q-tile 128 (32 q/wave),
// 64-key tiles. S^T = K*Q^T (K natural A-operand), V pre-transposed globally.
// LDS: K [kk][key][32], Vt [kf][d][32] (global_load_lds, m97 pattern), P padded.
#define LDP 72
#define NINF (-__builtin_inff())

__global__ __launch_bounds__(256, 2) void flash2_kernel(const u16* __restrict__ QKV,
                                                        const u16* __restrict__ Vt,
                                                        u16* __restrict__ Z) {
    __shared__ u16 lK[4][64 * 32];
    __shared__ u16 lV[2][128 * 32];
    __shared__ u16 lP[4][32 * LDP];
    int tid = threadIdx.x, wave = tid >> 6, lane = tid & 63;
    int quad = lane >> 4, l16 = lane & 15;
    int qt = 15 - (int)blockIdx.x;  // big tiles first
    int h = blockIdx.y, b = blockIdx.z;
    int kvh = h >> 2;
    int Q0 = qt * 128;
    int qw = Q0 + wave * 32;
    int lrow = lane >> 2, lcol = (lane & 3) * 8;

    // Q fragments (1/sqrt(128) pre-folded by rope)
    bf16x8 qf[2][4];
#pragma unroll
    for (int nt = 0; nt < 2; nt++) {
        const u16* qp = QKV + (size_t)(b * SEQ + qw + nt * 16 + l16) * QKVN + h * DHEAD;
#pragma unroll
        for (int kk = 0; kk < 4; kk++)
            qf[nt][kk] = *(const bf16x8*)(qp + kk * 32 + quad * 8);
    }

    f32x4 o[2][8] = {};
    float mrun[2] = {NINF, NINF};
    float lrun[2] = {0.f, 0.f};

    // staging bases
    const u16* gk = QKV + (size_t)(b * SEQ + lrow) * QKVN + DMODEL + kvh * DHEAD + wave * 32 + lcol;
    u16* lk = lK[wave];
    int kf_w = wave >> 1, dh_w = (wave & 1) * 64;
    const u16* gv = Vt + ((size_t)(b * NKV + kvh) * DHEAD + dh_w + lrow) * SEQ + kf_w * 32 + lcol;
    u16* lv = lV[kf_w] + dh_w * 32;

    int nkt = 2 * qt + 2;
    for (int kt = 0; kt < nkt; kt++) {
        int key0 = kt * 64;
        if (kt) __syncthreads();  // prev tile's reads done
#pragma unroll
        for (int g = 0; g < 4; g++)
            gload16(gk + (size_t)(key0 + g * 16) * QKVN, lk + g * 512);
#pragma unroll
        for (int g = 0; g < 4; g++)
            gload16(gv + (size_t)(g * 16) * SEQ + key0, lv + g * 512);
        __syncthreads();  // staged tile ready (vmcnt drained)

        if (key0 <= qw + 31) {
            // S^T: m=key (4 tiles), n=q (2 tiles)
            f32x4 st[4][2] = {};
#pragma unroll
            for (int kk = 0; kk < 4; kk++) {
                bf16x8 kfr[4];
#pragma unroll
                for (int mt = 0; mt < 4; mt++)
                    kfr[mt] = *(const bf16x8*)(lK[kk] + (mt * 16 + l16) * 32 + quad * 8);
#pragma unroll
                for (int mt = 0; mt < 4; mt++)
#pragma unroll
                    for (int nt = 0; nt < 2; nt++)
                        st[mt][nt] = mfma16(kfr[mt], qf[nt][kk], st[mt][nt]);
            }
            if (key0 + 63 > qw) {  // causal mask needed
#pragma unroll
                for (int mt = 0; mt < 4; mt++)
#pragma unroll
                    for (int nt = 0; nt < 2; nt++)
#pragma unroll
                        for (int r = 0; r < 4; r++)
                            if (key0 + mt * 16 + quad * 4 + r > qw + nt * 16 + l16)
                                st[mt][nt][r] = NINF;
            }
            float alpha[2];
#pragma unroll
            for (int nt = 0; nt < 2; nt++) {
                float vmax = NINF;
#pragma unroll
                for (int mt = 0; mt < 4; mt++)
#pragma unroll
                    for (int r = 0; r < 4; r++) vmax = fmaxf(vmax, st[mt][nt][r]);
                vmax = fmaxf(vmax, __shfl_xor(vmax, 16));
                vmax = fmaxf(vmax, __shfl_xor(vmax, 32));
                float mnew = fmaxf(mrun[nt], vmax);
                alpha[nt] = __expf(mrun[nt] - mnew);
                mrun[nt] = mnew;
                float rsum = 0.f;
#pragma unroll
                for (int mt = 0; mt < 4; mt++)
#pragma unroll
                    for (int r = 0; r < 4; r++) {
                        float p = __expf(st[mt][nt][r] - mnew);
                        st[mt][nt][r] = p;
                        rsum += p;
                    }
                rsum += __shfl_xor(rsum, 16);
                rsum += __shfl_xor(rsum, 32);
                lrun[nt] = lrun[nt] * alpha[nt] + rsum;
                // P -> LDS (b64 packed writes, row=q col=key)
#pragma unroll
                for (int mt = 0; mt < 4; mt++) {
                    u32 p01 = pack2bf(st[mt][nt][0], st[mt][nt][1]);
                    u32 p23 = pack2bf(st[mt][nt][2], st[mt][nt][3]);
                    uint2 pk; pk.x = p01; pk.y = p23;
                    *(uint2*)(lP[wave] + (nt * 16 + l16) * LDP + mt * 16 + quad * 4) = pk;
                }
            }
            // rescale O by alpha (broadcast to C-layout rows)
#pragma unroll
            for (int mtq = 0; mtq < 2; mtq++)
#pragma unroll
                for (int r = 0; r < 4; r++) {
                    float av = __shfl(alpha[mtq], quad * 4 + r);
#pragma unroll
                    for (int ntd = 0; ntd < 8; ntd++) o[mtq][ntd][r] *= av;
                }
            // PV: O[q][d] += P[q][key] * V[key][d]
#pragma unroll
            for (int kfi = 0; kfi < 2; kfi++) {
                bf16x8 pf0 = *(const bf16x8*)(lP[wave] + l16 * LDP + kfi * 32 + quad * 8);
                bf16x8 pf1 = *(const bf16x8*)(lP[wave] + (16 + l16) * LDP + kfi * 32 + quad * 8);
#pragma unroll
                for (int ntd = 0; ntd < 8; ntd++) {
                    bf16x8 vfr = *(const bf16x8*)(lV[kfi] + (ntd * 16 + l16) * 32 + quad * 8);
                    o[0][ntd] = mfma16(pf0, vfr, o[0][ntd]);
                    o[1][ntd] = mfma16(pf1, vfr, o[1][ntd]);
                }
            }
        }
    }
    // epilogue: O /= l
#pragma unroll
    for (int mtq = 0; mtq < 2; mtq++) {
        float linv[4];
#pragma unroll
        for (int r = 0; r < 4; r++) linv[r] = 1.0f / __shfl(lrun[mtq], quad * 4 + r);
#pragma unroll
        for (int ntd = 0; ntd < 8; ntd++)
#pragma unroll
            for (int r = 0; r < 4; r++) {
                int q = qw + mtq * 16 + quad * 4 + r;
                Z[(size_t)(b * SEQ + q) * DMODEL + h * DHEAD + ntd * 16 + l16] =
                    f2bf(o[mtq][ntd][r] * linv[r]);
            }
    }
}

extern "C" void kernel_launch(void* const* d_in, const int* in_sizes, int n_in,
                              void* d_out, int out_size, void* d_ws, size_t ws_size,
                              hipStream_t stream) {
    const float* x    = (const float*)d_in[0];
    const float* fcos = (const float*)d_in[1];
    const float* fsin = (const float*)d_in[2];
    const float* wq   = (const float*)d_in[3];
    const float* wk   = (const float*)d_in[4];
    const float* wv   = (const float*)d_in[5];
    const float* wo   = (const float*)d_in[6];
    float* out = (float*)d_out;
    char* ws = (char*)d_ws;

    const size_t MiB = 1024ull * 1024ull;
    u16* xb    = (u16*)(ws);              // 32MiB [4096][4096]; reused as zb after QKV gemm
    u16* zb    = xb;
    u16* wqkvt = (u16*)(ws + 32 * MiB);   // 48MiB [6144][4096]
    u16* wot   = (u16*)(ws + 80 * MiB);   // 32MiB [4096][4096]
    u16* qkv   = (u16*)(ws + 112 * MiB);  // 48MiB [4096][6144]
    u16* vtb   = (u16*)(ws + 160 * MiB);  // 8MiB  [2][1024][2048]

    f2bf_kernel<<<16384, 256, 0, stream>>>(x, xb, TOKENS * DMODEL);
    dim3 tb(32, 8);
    transpose_kernel<<<dim3(128, 128), tb, 0, stream>>>(wq, wqkvt, 4096, 4096);
    transpose_kernel<<<dim3(32, 128), tb, 0, stream>>>(wk, wqkvt + (size_t)4096 * 4096, 4096, 1024);
    transpose_kernel<<<dim3(32, 128), tb, 0, stream>>>(wv, wqkvt + (size_t)5120 * 4096, 4096, 1024);
    transpose_kernel<<<dim3(128, 128), tb, 0, stream>>>(wo, wot, 4096, 4096);

    gemm_lds<false><<<dim3(48, 32), 256, 0, stream>>>(xb, wqkvt, qkv, 4096, QKVN, 4096);

    rope2_kernel<<<32768, 256, 0, stream>>>(qkv, fcos, fsin, NHEAD, 0, 0.08838834764831845f);
    rope2_kernel<<<8192, 256, 0, stream>>>(qkv, fcos, fsin, NKV, DMODEL, 1.0f);

    vtrans_kernel<<<dim3(32, 64, 2), tb, 0, stream>>>(qkv, vtb);

    flash2_kernel<<<dim3(16, 32, 2), 256, 0, stream>>>(qkv, vtb, zb);

    gemm_lds<true><<<dim3(32, 32), 256, 0, stream>>>(zb, wot, out, 4096, 4096, 4096);
}